// Round 15
// baseline (316.582 us; speedup 1.0000x reference)
//
#include <hip/hip_runtime.h>
#include <stdint.h>

#define TT 512
#define BB 4096
#define NT8 512   // tiles of 8 batch columns
#define LOG2E 1.4426950408889634f

typedef _Float16 half8_t __attribute__((ext_vector_type(8)));
typedef _Float16 half4_t __attribute__((ext_vector_type(4)));
typedef __fp16 fp16x2_t __attribute__((ext_vector_type(2)));
typedef float f32x4 __attribute__((ext_vector_type(4)));
typedef float f32x2 __attribute__((ext_vector_type(2)));

union FragU  { uint4 u4; half8_t h8; };
union Frag2U { uint2 u2; half4_t h4; };
union PkU { fp16x2_t h2; unsigned int u; };

__device__ __forceinline__ float rcp_(float x){ return __builtin_amdgcn_rcpf(x); }
__device__ __forceinline__ float exp2_(float x){ return __builtin_amdgcn_exp2f(x); }
__device__ __forceinline__ float elu_(float x){ return x > 0.0f ? x : (exp2_(x * LOG2E) - 1.0f); }
__device__ __forceinline__ int mini_(int a, int b){ return a < b ? a : b; }
__device__ __forceinline__ unsigned int pkrne_(float a, float b){
    PkU p; p.h2[0] = (__fp16)a; p.h2[1] = (__fp16)b; return p.u;
}

__device__ __forceinline__ f32x4 MFMA32(half8_t a, half8_t b, f32x4 c) {
    return __builtin_amdgcn_mfma_f32_16x16x32_f16(a, b, c, 0, 0, 0);
}
__device__ __forceinline__ f32x4 MFMA16(half4_t a, half4_t b, f32x4 c) {
    return __builtin_amdgcn_mfma_f32_16x16x16f16(a, b, c, 0, 0, 0);
}

__device__ __forceinline__ f32x4 ld4_(const float* p){ return *(const f32x4*)p; }

// pack 8/4 f32 -> f16 with scale
__device__ __forceinline__ half8_t packA8s(const float* s, float sc) {
    half8_t h;
#pragma unroll
    for (int k = 0; k < 8; ++k) h[k] = (_Float16)(s[k] * sc);
    return h;
}
__device__ __forceinline__ half4_t packA4s(const float* s, float sc) {
    half4_t h;
#pragma unroll
    for (int k = 0; k < 4; ++k) h[k] = (_Float16)(s[k] * sc);
    return h;
}

// Two-unit LSTM cell, f32x2-packed, shared-rcp sigmoids.
// Inputs PRESCALED: i,f,o rows by log2e; g rows by 2*log2e.
// 7 trans/unit (5 exp2 + 2 rcp). |g'|<~24 -> P<2^96, no overflow.
__device__ __forceinline__ void cell2p_(f32x2 gi, f32x2 gf, f32x2 gg, f32x2 go,
                                        f32x2& c, f32x2& h) {
    f32x2 ei, ef, eg, eo;
    ei[0] = exp2_(-gi[0]); ei[1] = exp2_(-gi[1]);
    ef[0] = exp2_(-gf[0]); ef[1] = exp2_(-gf[1]);
    eg[0] = exp2_(-gg[0]); eg[1] = exp2_(-gg[1]);
    eo[0] = exp2_(-go[0]); eo[1] = exp2_(-go[1]);
    const f32x2 one = {1.0f, 1.0f};
    f32x2 ai = one + ei, af = one + ef, ag = one + eg, ao = one + eo;
    f32x2 pif = ai * af, pgo = ag * ao;
    f32x2 P = pif * pgo;
    f32x2 R; R[0] = rcp_(P[0]); R[1] = rcp_(P[1]);
    f32x2 I = R * (af * pgo);
    f32x2 F = R * (ai * pgo);
    f32x2 Gt = R * (pif * ao);
    f32x2 O = R * (pif * ag);
    f32x2 G = Gt + Gt - one;            // tanh(g) = 2*sigmoid(2g)-1
    c = F * c + I * G;
    f32x2 ct = c * (-2.0f * LOG2E);
    f32x2 et; et[0] = exp2_(ct[0]); et[1] = exp2_(ct[1]);
    f32x2 den = one + et;
    f32x2 Rt; Rt[0] = rcp_(den[0]); Rt[1] = rcp_(den[1]);
    f32x2 T = Rt + Rt - one;
    h = O * T;
}

// Dup-8 (8 real cols/chain, B col-slots 8-15 ≡ 0-7): lane (q,b), c=b&7,
// hi8=(b>=8) owns units uu=4q+2*hi8, uu+1 of col c, packed as u32 hh
// (2x fp16 RNE). fp16-only recurrence (error floor = fp16 ws quantization).
//
// K=16 h-MFMA (mfma_f32_16x16x16f16): B lane(q,b) holds rows 4q..4q+3 of
// col b = units {4q,4q+1} [owner = self or lane^8] and {4q+2,4q+3}
// [owner = the other one]. So the ENTIRE h-exchange is:
//     swp = __shfl_xor(hh, 8);  w0 = b<8 ? hh : swp;  w1 = b<8 ? swp : hh;
// one ds_swizzle + 2 cndmask — no LDS, no barrier, no round-trip.
// A lane(q,b) = row b, cols 4q..4q+3 of Whh — all lanes real, no padding.
// C layout (shape-determined): reg r of lane(q,b) = gate row 16m+4q+r, col b.

// ---------------- phase A: layer 0 (input dim 1), both directions ----------------
// C-in (bias + Wih*x[t]) precomputed ONE STEP AHEAD (ping-pong) from the
// prefetched x — off the recurrence chain (r12's proven wiM pattern).
struct PA {
    const float *x;
    const float *WihF, *WhhF, *bihF, *bhhF;
    const float *WihB, *WhhB, *bihB, *bhhB;
    char* ws;   // [tile8][t][512B]: col c at c*64: [f u0-15 hi | b u0-15 hi] fp16
};

__global__ __launch_bounds__(256) void phaseA_k(PA p) {
    const int tid = threadIdx.x;
    const int lane = tid & 63;
    const int wv   = tid >> 6;
    const int q = lane >> 4, b = lane & 15, c = b & 7;
    const bool hi8 = b >= 8;
    const int chain = blockIdx.x * 4 + wv;       // 1024 chains = 512 tiles x 2 dirs
    const int tile = chain >> 1, dir = chain & 1;

    const float* Wih = dir ? p.WihB : p.WihF;
    const float* Whh = dir ? p.WhhB : p.WhhF;
    const float* bih = dir ? p.bihB : p.bihF;
    const float* bhh = dir ? p.bhhB : p.bhhF;

    const float SC0 = LOG2E, SC1 = LOG2E, SC2 = 2.0f*LOG2E, SC3 = LOG2E;

    // A-frags (K=16): row b, cols 4q..4q+3
    half4_t A0 = packA4s(Whh + (     b)*16 + 4*q, SC0);
    half4_t A1 = packA4s(Whh + (16 + b)*16 + 4*q, SC1);
    half4_t A2 = packA4s(Whh + (32 + b)*16 + 4*q, SC2);
    half4_t A3 = packA4s(Whh + (48 + b)*16 + 4*q, SC3);

    f32x4 bias0 = (ld4_(bih +      4*q) + ld4_(bhh +      4*q)) * SC0;
    f32x4 bias1 = (ld4_(bih + 16 + 4*q) + ld4_(bhh + 16 + 4*q)) * SC1;
    f32x4 bias2 = (ld4_(bih + 32 + 4*q) + ld4_(bhh + 32 + 4*q)) * SC2;
    f32x4 bias3 = (ld4_(bih + 48 + 4*q) + ld4_(bhh + 48 + 4*q)) * SC3;

    f32x4 wihx0 = ld4_(Wih +      4*q) * SC0;   // Wih0 is [64 x 1]
    f32x4 wihx1 = ld4_(Wih + 16 + 4*q) * SC1;
    f32x4 wihx2 = ld4_(Wih + 32 + 4*q) * SC2;
    f32x4 wihx3 = ld4_(Wih + 48 + 4*q) * SC3;

    const int uu = 4*q + (hi8 ? 2 : 0);
    unsigned int hh = 0u;
    f32x2 cc = {0.f, 0.f};

    const char* xbase = (const char*)p.x + (size_t)tile*8*TT*4;   // uniform
    const int   xoff  = c*TT*4;                                   // invariant voffset
    char*       wsbase = p.ws + (size_t)tile*TT*512;              // uniform
    const int   woff  = c*64 + dir*32 + uu*2;

    auto xld = [&](int s_)->float {
        int s = mini_(s_, TT-1);
        int t = dir ? (TT-1-s) : s;
        return *(const float*)(xbase + (size_t)t*4 + xoff);
    };

    auto mkCin = [&](float xv, f32x4& o0, f32x4& o1, f32x4& o2, f32x4& o3) {
        o0 = bias0 + wihx0 * xv;
        o1 = bias1 + wihx1 * xv;
        o2 = bias2 + wihx2 * xv;
        o3 = bias3 + wihx3 * xv;
    };

    auto step = [&](f32x4 p0, f32x4 p1, f32x4 p2, f32x4 p3, int t) {
        unsigned int swp = (unsigned int)__shfl_xor((int)hh, 8);
        Frag2U bf;
        bf.u2.x = hi8 ? swp : hh;
        bf.u2.y = hi8 ? hh : swp;
        f32x4 r0 = MFMA16(A0, bf.h4, p0);
        f32x4 r1 = MFMA16(A1, bf.h4, p1);
        f32x4 r2 = MFMA16(A2, bf.h4, p2);
        f32x4 r3 = MFMA16(A3, bf.h4, p3);
        f32x2 gi, gf, gg, go;
        gi[0] = hi8 ? r0[2] : r0[0]; gi[1] = hi8 ? r0[3] : r0[1];
        gf[0] = hi8 ? r1[2] : r1[0]; gf[1] = hi8 ? r1[3] : r1[1];
        gg[0] = hi8 ? r2[2] : r2[0]; gg[1] = hi8 ? r2[3] : r2[1];
        go[0] = hi8 ? r3[2] : r3[0]; go[1] = hi8 ? r3[3] : r3[1];
        f32x2 hv;
        cell2p_(gi, gf, gg, go, cc, hv);
        hh = pkrne_(hv[0], hv[1]);
        *(unsigned int*)(wsbase + (size_t)t*512 + woff) = hh;
    };

    float xv0 = xld(0), xv1 = xld(1), xv2 = xld(2), xv3 = xld(3);
    f32x4 ca0, ca1, ca2, ca3, cb0, cb1, cb2, cb3;
    mkCin(xv0, ca0, ca1, ca2, ca3);
    for (int s = 0; s < TT; s += 4) {
        const int t0 = dir ? (TT-1-s) : s;
        const int d  = dir ? -1 : 1;
        mkCin(xv1, cb0, cb1, cb2, cb3);
        step(ca0, ca1, ca2, ca3, t0);        xv0 = xld(s+4);
        mkCin(xv2, ca0, ca1, ca2, ca3);
        step(cb0, cb1, cb2, cb3, t0 + d);    xv1 = xld(s+5);
        mkCin(xv3, cb0, cb1, cb2, cb3);
        step(ca0, ca1, ca2, ca3, t0 + 2*d);  xv2 = xld(s+6);
        mkCin(xv0, ca0, ca1, ca2, ca3);      // s+4 (xv0 already reloaded)
        step(cb0, cb1, cb2, cb3, t0 + 3*d);  xv3 = xld(s+7);
    }
}

// ---------------- phase B: layer 1 (input dim 32 from ws), both directions ----------------
// wi-MFMAs (K=32, prefetched ws) precomputed one step ahead (r12-proven);
// wh side uses the K=16 shfl_xor exchange — no LDS at all.
struct PB {
    const float *WihF, *WhhF, *bihF, *bhhF;
    const float *WihB, *WhhB, *bihB, *bhhB;
    const char* ws;
    float* hT;   // [dir][batch][16] f32
};

__global__ __launch_bounds__(256) void phaseB_k(PB p) {
    const int tid = threadIdx.x;
    const int lane = tid & 63;
    const int wv   = tid >> 6;
    const int q = lane >> 4, b = lane & 15, c = b & 7;
    const bool hi8 = b >= 8;
    const int chain = blockIdx.x * 4 + wv;
    const int tile = chain >> 1, dir = chain & 1;

    const float* Wih = dir ? p.WihB : p.WihF;
    const float* Whh = dir ? p.WhhB : p.WhhF;
    const float* bih = dir ? p.bihB : p.bihF;
    const float* bhh = dir ? p.bhhB : p.bhhF;

    const float SC0 = LOG2E, SC1 = LOG2E, SC2 = 2.0f*LOG2E, SC3 = LOG2E;

    half8_t wi0 = packA8s(Wih + (     b)*32 + 8*q, SC0);  // K=32 = [h0f;h0b]
    half8_t wi1 = packA8s(Wih + (16 + b)*32 + 8*q, SC1);
    half8_t wi2 = packA8s(Wih + (32 + b)*32 + 8*q, SC2);
    half8_t wi3 = packA8s(Wih + (48 + b)*32 + 8*q, SC3);

    // wh (K=16): row b, cols 4q..4q+3 — all lanes real
    half4_t wh0 = packA4s(Whh + (     b)*16 + 4*q, SC0);
    half4_t wh1 = packA4s(Whh + (16 + b)*16 + 4*q, SC1);
    half4_t wh2 = packA4s(Whh + (32 + b)*16 + 4*q, SC2);
    half4_t wh3 = packA4s(Whh + (48 + b)*16 + 4*q, SC3);

    f32x4 bias0 = (ld4_(bih +      4*q) + ld4_(bhh +      4*q)) * SC0;
    f32x4 bias1 = (ld4_(bih + 16 + 4*q) + ld4_(bhh + 16 + 4*q)) * SC1;
    f32x4 bias2 = (ld4_(bih + 32 + 4*q) + ld4_(bhh + 32 + 4*q)) * SC2;
    f32x4 bias3 = (ld4_(bih + 48 + 4*q) + ld4_(bhh + 48 + 4*q)) * SC3;

    const int uu = 4*q + (hi8 ? 2 : 0);
    unsigned int hh = 0u;
    f32x2 cc = {0.f, 0.f};
    f32x2 hv = {0.f, 0.f};

    const char* wsbase = p.ws + (size_t)tile*TT*512;   // uniform
    const int   xoff   = c*64 + q*16;                  // invariant voffset

    auto xld = [&](int s_)->uint4 {
        int s = mini_(s_, TT-1);
        int t = dir ? (TT-1-s) : s;
        return *(const uint4*)(wsbase + (size_t)t*512 + xoff);
    };

    auto wiM = [&](uint4 xin, f32x4& o0, f32x4& o1, f32x4& o2, f32x4& o3) {
        FragU xf; xf.u4 = xin;
        o0 = MFMA32(wi0, xf.h8, bias0);
        o1 = MFMA32(wi1, xf.h8, bias1);
        o2 = MFMA32(wi2, xf.h8, bias2);
        o3 = MFMA32(wi3, xf.h8, bias3);
    };

    auto stepWh = [&](f32x4 p0, f32x4 p1, f32x4 p2, f32x4 p3) {
        unsigned int swp = (unsigned int)__shfl_xor((int)hh, 8);
        Frag2U bf;
        bf.u2.x = hi8 ? swp : hh;
        bf.u2.y = hi8 ? hh : swp;
        f32x4 r0 = MFMA16(wh0, bf.h4, p0);
        f32x4 r1 = MFMA16(wh1, bf.h4, p1);
        f32x4 r2 = MFMA16(wh2, bf.h4, p2);
        f32x4 r3 = MFMA16(wh3, bf.h4, p3);
        f32x2 gi, gf, gg, go;
        gi[0] = hi8 ? r0[2] : r0[0]; gi[1] = hi8 ? r0[3] : r0[1];
        gf[0] = hi8 ? r1[2] : r1[0]; gf[1] = hi8 ? r1[3] : r1[1];
        gg[0] = hi8 ? r2[2] : r2[0]; gg[1] = hi8 ? r2[3] : r2[1];
        go[0] = hi8 ? r3[2] : r3[0]; go[1] = hi8 ? r3[3] : r3[1];
        cell2p_(gi, gf, gg, go, cc, hv);
        hh = pkrne_(hv[0], hv[1]);
    };

    uint4 xb0 = xld(0), xb1 = xld(1), xb2 = xld(2), xb3 = xld(3);
    f32x4 pa0, pa1, pa2, pa3, pb0, pb1, pb2, pb3;
    wiM(xb0, pa0, pa1, pa2, pa3);
    for (int s = 0; s < TT; s += 4) {
        wiM(xb1, pb0, pb1, pb2, pb3);      // step s+1's input side
        stepWh(pa0, pa1, pa2, pa3);        // step s
        xb0 = xld(s+4);
        wiM(xb2, pa0, pa1, pa2, pa3);      // step s+2
        stepWh(pb0, pb1, pb2, pb3);        // step s+1
        xb1 = xld(s+5);
        wiM(xb3, pb0, pb1, pb2, pb3);      // step s+3
        stepWh(pa0, pa1, pa2, pa3);        // step s+2
        xb2 = xld(s+6);
        wiM(xb0, pa0, pa1, pa2, pa3);      // step s+4 (xb0 already reloaded)
        stepWh(pb0, pb1, pb2, pb3);        // step s+3
        xb3 = xld(s+7);
    }

    const int batch = tile*8 + c;
    float* hp = p.hT + ((size_t)(dir ? BB : 0) + batch)*16 + uu;
    float2 ho; ho.x = hv[0]; ho.y = hv[1];
    *(float2*)hp = ho;
}

// ---------------- phase C: MLP head ----------------
struct PC {
    const float* hT;
    const float *W1, *b1, *W2, *b2;
    float* out;
};

__global__ __launch_bounds__(64) void head_k(PC p) {
    const int B = blockIdx.x * 64 + threadIdx.x;
    const float* hf = p.hT + (size_t)B*16;
    const float* hb = p.hT + ((size_t)BB + B)*16;

    float z0[32];
#pragma unroll
    for (int k = 0; k < 16; ++k) z0[k] = elu_(hb[k]);       // feat = [hT_b, hT_f]
#pragma unroll
    for (int k = 0; k < 16; ++k) z0[16+k] = elu_(hf[k]);

    float z1[25];
#pragma unroll
    for (int o = 0; o < 25; ++o) {
        float a = p.b1[o];
#pragma unroll
        for (int k = 0; k < 32; ++k) a = fmaf(p.W1[o*32 + k], z0[k], a);
        z1[o] = elu_(a);
    }
#pragma unroll
    for (int o = 0; o < 20; ++o) {
        float a = p.b2[o];
#pragma unroll
        for (int k = 0; k < 25; ++k) a = fmaf(p.W2[o*25 + k], z1[k], a);
        p.out[(size_t)B*20 + o] = elu_(a);
    }
}

extern "C" void kernel_launch(void* const* d_in, const int* in_sizes, int n_in,
                              void* d_out, int out_size, void* d_ws, size_t ws_size,
                              hipStream_t stream) {
    (void)in_sizes; (void)n_in; (void)out_size;

    const size_t frag_bytes = (size_t)NT8 * TT * 512;                 // 128 MiB
    const size_t hT_bytes   = (size_t)2 * BB * 16 * sizeof(float);    // 512 KiB
    size_t hT_off = (ws_size >= frag_bytes + hT_bytes) ? frag_bytes
                                                       : (ws_size - hT_bytes);
    char* ws = (char*)d_ws;
    float* hT = (float*)(ws + hT_off);

    PA pa;
    pa.x = (const float*)d_in[0];
    pa.WihF = (const float*)d_in[1];  pa.WhhF = (const float*)d_in[2];
    pa.bihF = (const float*)d_in[3];  pa.bhhF = (const float*)d_in[4];
    pa.WihB = (const float*)d_in[5];  pa.WhhB = (const float*)d_in[6];
    pa.bihB = (const float*)d_in[7];  pa.bhhB = (const float*)d_in[8];
    pa.ws = ws;
    hipLaunchKernelGGL(phaseA_k, dim3(256), dim3(256), 0, stream, pa);

    PB pb;
    pb.WihF = (const float*)d_in[9];   pb.WhhF = (const float*)d_in[10];
    pb.bihF = (const float*)d_in[11];  pb.bhhF = (const float*)d_in[12];
    pb.WihB = (const float*)d_in[13];  pb.WhhB = (const float*)d_in[14];
    pb.bihB = (const float*)d_in[15];  pb.bhhB = (const float*)d_in[16];
    pb.ws = ws; pb.hT = hT;
    hipLaunchKernelGGL(phaseB_k, dim3(256), dim3(256), 0, stream, pb);

    PC pc;
    pc.hT = hT;
    pc.W1 = (const float*)d_in[17]; pc.b1 = (const float*)d_in[18];
    pc.W2 = (const float*)d_in[19]; pc.b2 = (const float*)d_in[20];
    pc.out = (float*)d_out;
    hipLaunchKernelGGL(head_k, dim3(BB/64), dim3(64), 0, stream, pc);
}

// Round 16
// 298.840 us; speedup vs baseline: 1.0594x; 1.0594x over previous
//
#include <hip/hip_runtime.h>
#include <stdint.h>

#define TT 512
#define BB 4096
#define NT8 512   // tiles of 8 batch columns
#define LOG2E 1.4426950408889634f

typedef _Float16 half8_t __attribute__((ext_vector_type(8)));
typedef _Float16 half4_t __attribute__((ext_vector_type(4)));
typedef __fp16 fp16x2_t __attribute__((ext_vector_type(2)));
typedef float f32x4 __attribute__((ext_vector_type(4)));
typedef float f32x2 __attribute__((ext_vector_type(2)));

union FragU  { uint4 u4; half8_t h8; };
union Frag2U { uint2 u2; half4_t h4; };
union PkU { fp16x2_t h2; unsigned int u; };

__device__ __forceinline__ float rcp_(float x){ return __builtin_amdgcn_rcpf(x); }
__device__ __forceinline__ float exp2_(float x){ return __builtin_amdgcn_exp2f(x); }
__device__ __forceinline__ float elu_(float x){ return x > 0.0f ? x : (exp2_(x * LOG2E) - 1.0f); }
__device__ __forceinline__ int mini_(int a, int b){ return a < b ? a : b; }
__device__ __forceinline__ unsigned int pkrne_(float a, float b){
    PkU p; p.h2[0] = (__fp16)a; p.h2[1] = (__fp16)b; return p.u;
}

// lane <-> lane^8 exchange as a pure-VALU DPP op: within each 16-lane row,
// (i+8)%16 == i^8, so row_ror:8 (dpp_ctrl 0x128) does it. No LDS unit,
// no lgkmcnt — ~2-cyc latency vs ~60-120 for ds_bpermute/ds_swizzle.
__device__ __forceinline__ unsigned int xor8_dpp_(unsigned int v){
    return (unsigned int)__builtin_amdgcn_update_dpp(0, (int)v, 0x128, 0xF, 0xF, true);
}

__device__ __forceinline__ f32x4 MFMA32(half8_t a, half8_t b, f32x4 c) {
    return __builtin_amdgcn_mfma_f32_16x16x32_f16(a, b, c, 0, 0, 0);
}
__device__ __forceinline__ f32x4 MFMA16(half4_t a, half4_t b, f32x4 c) {
    return __builtin_amdgcn_mfma_f32_16x16x16f16(a, b, c, 0, 0, 0);
}

__device__ __forceinline__ f32x4 ld4_(const float* p){ return *(const f32x4*)p; }

// pack 8/4 f32 -> f16 with scale
__device__ __forceinline__ half8_t packA8s(const float* s, float sc) {
    half8_t h;
#pragma unroll
    for (int k = 0; k < 8; ++k) h[k] = (_Float16)(s[k] * sc);
    return h;
}
__device__ __forceinline__ half4_t packA4s(const float* s, float sc) {
    half4_t h;
#pragma unroll
    for (int k = 0; k < 4; ++k) h[k] = (_Float16)(s[k] * sc);
    return h;
}

// Two-unit LSTM cell, f32x2-packed, shared-rcp sigmoids.
// Inputs PRESCALED: i,f,o rows by log2e; g rows by 2*log2e.
// 7 trans/unit (5 exp2 + 2 rcp). |g'|<~24 -> P<2^96, no overflow.
__device__ __forceinline__ void cell2p_(f32x2 gi, f32x2 gf, f32x2 gg, f32x2 go,
                                        f32x2& c, f32x2& h) {
    f32x2 ei, ef, eg, eo;
    ei[0] = exp2_(-gi[0]); ei[1] = exp2_(-gi[1]);
    ef[0] = exp2_(-gf[0]); ef[1] = exp2_(-gf[1]);
    eg[0] = exp2_(-gg[0]); eg[1] = exp2_(-gg[1]);
    eo[0] = exp2_(-go[0]); eo[1] = exp2_(-go[1]);
    const f32x2 one = {1.0f, 1.0f};
    f32x2 ai = one + ei, af = one + ef, ag = one + eg, ao = one + eo;
    f32x2 pif = ai * af, pgo = ag * ao;
    f32x2 P = pif * pgo;
    f32x2 R; R[0] = rcp_(P[0]); R[1] = rcp_(P[1]);
    f32x2 I = R * (af * pgo);
    f32x2 F = R * (ai * pgo);
    f32x2 Gt = R * (pif * ao);
    f32x2 O = R * (pif * ag);
    f32x2 G = Gt + Gt - one;            // tanh(g) = 2*sigmoid(2g)-1
    c = F * c + I * G;
    f32x2 ct = c * (-2.0f * LOG2E);
    f32x2 et; et[0] = exp2_(ct[0]); et[1] = exp2_(ct[1]);
    f32x2 den = one + et;
    f32x2 Rt; Rt[0] = rcp_(den[0]); Rt[1] = rcp_(den[1]);
    f32x2 T = Rt + Rt - one;
    h = O * T;
}

// Dup-8 (8 real cols/chain, B col-slots 8-15 ≡ 0-7): lane (q,b), c=b&7,
// hi8=(b>=8) owns units uu=4q+2*hi8, uu+1 of col c, packed as u32 hh
// (2x fp16 RNE). fp16-only recurrence (error floor = fp16 ws quantization).
//
// K=16 h-MFMA (mfma_f32_16x16x16f16): B lane(q,b) holds rows 4q..4q+3 of
// col b = units {4q,4q+1} [owner = self or lane^8] and {4q+2,4q+3}
// [owner = the other one]. Exchange (HW-verified r15):
//     swp = xor8_dpp(hh);  w0 = b<8 ? hh : swp;  w1 = b<8 ? swp : hh;
// A lane(q,b) = row b, cols 4q..4q+3 of Whh — all lanes real, no padding.
// C layout: reg r of lane(q,b) = gate row 16m+4q+r, col b.

// ---------------- phase A: layer 0 (input dim 1), both directions ----------------
// C-in (bias + Wih*x[t]) precomputed ONE STEP AHEAD (ping-pong) from the
// prefetched x — off the recurrence chain.
struct PA {
    const float *x;
    const float *WihF, *WhhF, *bihF, *bhhF;
    const float *WihB, *WhhB, *bihB, *bhhB;
    char* ws;   // [tile8][t][512B]: col c at c*64: [f u0-15 hi | b u0-15 hi] fp16
};

__global__ __launch_bounds__(256) void phaseA_k(PA p) {
    const int tid = threadIdx.x;
    const int lane = tid & 63;
    const int wv   = tid >> 6;
    const int q = lane >> 4, b = lane & 15, c = b & 7;
    const bool hi8 = b >= 8;
    const int chain = blockIdx.x * 4 + wv;       // 1024 chains = 512 tiles x 2 dirs
    const int tile = chain >> 1, dir = chain & 1;

    const float* Wih = dir ? p.WihB : p.WihF;
    const float* Whh = dir ? p.WhhB : p.WhhF;
    const float* bih = dir ? p.bihB : p.bihF;
    const float* bhh = dir ? p.bhhB : p.bhhF;

    const float SC0 = LOG2E, SC1 = LOG2E, SC2 = 2.0f*LOG2E, SC3 = LOG2E;

    // A-frags (K=16): row b, cols 4q..4q+3
    half4_t A0 = packA4s(Whh + (     b)*16 + 4*q, SC0);
    half4_t A1 = packA4s(Whh + (16 + b)*16 + 4*q, SC1);
    half4_t A2 = packA4s(Whh + (32 + b)*16 + 4*q, SC2);
    half4_t A3 = packA4s(Whh + (48 + b)*16 + 4*q, SC3);

    f32x4 bias0 = (ld4_(bih +      4*q) + ld4_(bhh +      4*q)) * SC0;
    f32x4 bias1 = (ld4_(bih + 16 + 4*q) + ld4_(bhh + 16 + 4*q)) * SC1;
    f32x4 bias2 = (ld4_(bih + 32 + 4*q) + ld4_(bhh + 32 + 4*q)) * SC2;
    f32x4 bias3 = (ld4_(bih + 48 + 4*q) + ld4_(bhh + 48 + 4*q)) * SC3;

    f32x4 wihx0 = ld4_(Wih +      4*q) * SC0;   // Wih0 is [64 x 1]
    f32x4 wihx1 = ld4_(Wih + 16 + 4*q) * SC1;
    f32x4 wihx2 = ld4_(Wih + 32 + 4*q) * SC2;
    f32x4 wihx3 = ld4_(Wih + 48 + 4*q) * SC3;

    const int uu = 4*q + (hi8 ? 2 : 0);
    unsigned int hh = 0u;
    f32x2 cc = {0.f, 0.f};

    const char* xbase = (const char*)p.x + (size_t)tile*8*TT*4;   // uniform
    const int   xoff  = c*TT*4;                                   // invariant voffset
    char*       wsbase = p.ws + (size_t)tile*TT*512;              // uniform
    const int   woff  = c*64 + dir*32 + uu*2;

    auto xld = [&](int s_)->float {
        int s = mini_(s_, TT-1);
        int t = dir ? (TT-1-s) : s;
        return *(const float*)(xbase + (size_t)t*4 + xoff);
    };

    auto mkCin = [&](float xv, f32x4& o0, f32x4& o1, f32x4& o2, f32x4& o3) {
        o0 = bias0 + wihx0 * xv;
        o1 = bias1 + wihx1 * xv;
        o2 = bias2 + wihx2 * xv;
        o3 = bias3 + wihx3 * xv;
    };

    auto step = [&](f32x4 p0, f32x4 p1, f32x4 p2, f32x4 p3, int t) {
        unsigned int swp = xor8_dpp_(hh);
        Frag2U bf;
        bf.u2.x = hi8 ? swp : hh;
        bf.u2.y = hi8 ? hh : swp;
        f32x4 r0 = MFMA16(A0, bf.h4, p0);
        f32x4 r1 = MFMA16(A1, bf.h4, p1);
        f32x4 r2 = MFMA16(A2, bf.h4, p2);
        f32x4 r3 = MFMA16(A3, bf.h4, p3);
        f32x2 gi, gf, gg, go;
        gi[0] = hi8 ? r0[2] : r0[0]; gi[1] = hi8 ? r0[3] : r0[1];
        gf[0] = hi8 ? r1[2] : r1[0]; gf[1] = hi8 ? r1[3] : r1[1];
        gg[0] = hi8 ? r2[2] : r2[0]; gg[1] = hi8 ? r2[3] : r2[1];
        go[0] = hi8 ? r3[2] : r3[0]; go[1] = hi8 ? r3[3] : r3[1];
        f32x2 hv;
        cell2p_(gi, gf, gg, go, cc, hv);
        hh = pkrne_(hv[0], hv[1]);
        *(unsigned int*)(wsbase + (size_t)t*512 + woff) = hh;
    };

    float xv0 = xld(0), xv1 = xld(1), xv2 = xld(2), xv3 = xld(3);
    f32x4 ca0, ca1, ca2, ca3, cb0, cb1, cb2, cb3;
    mkCin(xv0, ca0, ca1, ca2, ca3);
    for (int s = 0; s < TT; s += 4) {
        const int t0 = dir ? (TT-1-s) : s;
        const int d  = dir ? -1 : 1;
        mkCin(xv1, cb0, cb1, cb2, cb3);
        step(ca0, ca1, ca2, ca3, t0);        xv0 = xld(s+4);
        mkCin(xv2, ca0, ca1, ca2, ca3);
        step(cb0, cb1, cb2, cb3, t0 + d);    xv1 = xld(s+5);
        mkCin(xv3, cb0, cb1, cb2, cb3);
        step(ca0, ca1, ca2, ca3, t0 + 2*d);  xv2 = xld(s+6);
        mkCin(xv0, ca0, ca1, ca2, ca3);      // s+4 (xv0 already reloaded)
        step(cb0, cb1, cb2, cb3, t0 + 3*d);  xv3 = xld(s+7);
    }
}

// ---------------- phase B: layer 1 (input dim 32 from ws), both directions ----------------
// wi-MFMAs (K=32, prefetched ws) precomputed one step ahead;
// wh side uses the K=16 DPP exchange — no LDS at all.
struct PB {
    const float *WihF, *WhhF, *bihF, *bhhF;
    const float *WihB, *WhhB, *bihB, *bhhB;
    const char* ws;
    float* hT;   // [dir][batch][16] f32
};

__global__ __launch_bounds__(256) void phaseB_k(PB p) {
    const int tid = threadIdx.x;
    const int lane = tid & 63;
    const int wv   = tid >> 6;
    const int q = lane >> 4, b = lane & 15, c = b & 7;
    const bool hi8 = b >= 8;
    const int chain = blockIdx.x * 4 + wv;
    const int tile = chain >> 1, dir = chain & 1;

    const float* Wih = dir ? p.WihB : p.WihF;
    const float* Whh = dir ? p.WhhB : p.WhhF;
    const float* bih = dir ? p.bihB : p.bihF;
    const float* bhh = dir ? p.bhhB : p.bhhF;

    const float SC0 = LOG2E, SC1 = LOG2E, SC2 = 2.0f*LOG2E, SC3 = LOG2E;

    half8_t wi0 = packA8s(Wih + (     b)*32 + 8*q, SC0);  // K=32 = [h0f;h0b]
    half8_t wi1 = packA8s(Wih + (16 + b)*32 + 8*q, SC1);
    half8_t wi2 = packA8s(Wih + (32 + b)*32 + 8*q, SC2);
    half8_t wi3 = packA8s(Wih + (48 + b)*32 + 8*q, SC3);

    // wh (K=16): row b, cols 4q..4q+3 — all lanes real
    half4_t wh0 = packA4s(Whh + (     b)*16 + 4*q, SC0);
    half4_t wh1 = packA4s(Whh + (16 + b)*16 + 4*q, SC1);
    half4_t wh2 = packA4s(Whh + (32 + b)*16 + 4*q, SC2);
    half4_t wh3 = packA4s(Whh + (48 + b)*16 + 4*q, SC3);

    f32x4 bias0 = (ld4_(bih +      4*q) + ld4_(bhh +      4*q)) * SC0;
    f32x4 bias1 = (ld4_(bih + 16 + 4*q) + ld4_(bhh + 16 + 4*q)) * SC1;
    f32x4 bias2 = (ld4_(bih + 32 + 4*q) + ld4_(bhh + 32 + 4*q)) * SC2;
    f32x4 bias3 = (ld4_(bih + 48 + 4*q) + ld4_(bhh + 48 + 4*q)) * SC3;

    const int uu = 4*q + (hi8 ? 2 : 0);
    unsigned int hh = 0u;
    f32x2 cc = {0.f, 0.f};
    f32x2 hv = {0.f, 0.f};

    const char* wsbase = p.ws + (size_t)tile*TT*512;   // uniform
    const int   xoff   = c*64 + q*16;                  // invariant voffset

    auto xld = [&](int s_)->uint4 {
        int s = mini_(s_, TT-1);
        int t = dir ? (TT-1-s) : s;
        return *(const uint4*)(wsbase + (size_t)t*512 + xoff);
    };

    auto wiM = [&](uint4 xin, f32x4& o0, f32x4& o1, f32x4& o2, f32x4& o3) {
        FragU xf; xf.u4 = xin;
        o0 = MFMA32(wi0, xf.h8, bias0);
        o1 = MFMA32(wi1, xf.h8, bias1);
        o2 = MFMA32(wi2, xf.h8, bias2);
        o3 = MFMA32(wi3, xf.h8, bias3);
    };

    auto stepWh = [&](f32x4 p0, f32x4 p1, f32x4 p2, f32x4 p3) {
        unsigned int swp = xor8_dpp_(hh);
        Frag2U bf;
        bf.u2.x = hi8 ? swp : hh;
        bf.u2.y = hi8 ? hh : swp;
        f32x4 r0 = MFMA16(wh0, bf.h4, p0);
        f32x4 r1 = MFMA16(wh1, bf.h4, p1);
        f32x4 r2 = MFMA16(wh2, bf.h4, p2);
        f32x4 r3 = MFMA16(wh3, bf.h4, p3);
        f32x2 gi, gf, gg, go;
        gi[0] = hi8 ? r0[2] : r0[0]; gi[1] = hi8 ? r0[3] : r0[1];
        gf[0] = hi8 ? r1[2] : r1[0]; gf[1] = hi8 ? r1[3] : r1[1];
        gg[0] = hi8 ? r2[2] : r2[0]; gg[1] = hi8 ? r2[3] : r2[1];
        go[0] = hi8 ? r3[2] : r3[0]; go[1] = hi8 ? r3[3] : r3[1];
        cell2p_(gi, gf, gg, go, cc, hv);
        hh = pkrne_(hv[0], hv[1]);
    };

    uint4 xb0 = xld(0), xb1 = xld(1), xb2 = xld(2), xb3 = xld(3);
    f32x4 pa0, pa1, pa2, pa3, pb0, pb1, pb2, pb3;
    wiM(xb0, pa0, pa1, pa2, pa3);
    for (int s = 0; s < TT; s += 4) {
        wiM(xb1, pb0, pb1, pb2, pb3);      // step s+1's input side
        stepWh(pa0, pa1, pa2, pa3);        // step s
        xb0 = xld(s+4);
        wiM(xb2, pa0, pa1, pa2, pa3);      // step s+2
        stepWh(pb0, pb1, pb2, pb3);        // step s+1
        xb1 = xld(s+5);
        wiM(xb3, pb0, pb1, pb2, pb3);      // step s+3
        stepWh(pa0, pa1, pa2, pa3);        // step s+2
        xb2 = xld(s+6);
        wiM(xb0, pa0, pa1, pa2, pa3);      // step s+4 (xb0 already reloaded)
        stepWh(pb0, pb1, pb2, pb3);        // step s+3
        xb3 = xld(s+7);
    }

    const int batch = tile*8 + c;
    float* hp = p.hT + ((size_t)(dir ? BB : 0) + batch)*16 + uu;
    float2 ho; ho.x = hv[0]; ho.y = hv[1];
    *(float2*)hp = ho;
}

// ---------------- phase C: MLP head ----------------
struct PC {
    const float* hT;
    const float *W1, *b1, *W2, *b2;
    float* out;
};

__global__ __launch_bounds__(64) void head_k(PC p) {
    const int B = blockIdx.x * 64 + threadIdx.x;
    const float* hf = p.hT + (size_t)B*16;
    const float* hb = p.hT + ((size_t)BB + B)*16;

    float z0[32];
#pragma unroll
    for (int k = 0; k < 16; ++k) z0[k] = elu_(hb[k]);       // feat = [hT_b, hT_f]
#pragma unroll
    for (int k = 0; k < 16; ++k) z0[16+k] = elu_(hf[k]);

    float z1[25];
#pragma unroll
    for (int o = 0; o < 25; ++o) {
        float a = p.b1[o];
#pragma unroll
        for (int k = 0; k < 32; ++k) a = fmaf(p.W1[o*32 + k], z0[k], a);
        z1[o] = elu_(a);
    }
#pragma unroll
    for (int o = 0; o < 20; ++o) {
        float a = p.b2[o];
#pragma unroll
        for (int k = 0; k < 25; ++k) a = fmaf(p.W2[o*25 + k], z1[k], a);
        p.out[(size_t)B*20 + o] = elu_(a);
    }
}

extern "C" void kernel_launch(void* const* d_in, const int* in_sizes, int n_in,
                              void* d_out, int out_size, void* d_ws, size_t ws_size,
                              hipStream_t stream) {
    (void)in_sizes; (void)n_in; (void)out_size;

    const size_t frag_bytes = (size_t)NT8 * TT * 512;                 // 128 MiB
    const size_t hT_bytes   = (size_t)2 * BB * 16 * sizeof(float);    // 512 KiB
    size_t hT_off = (ws_size >= frag_bytes + hT_bytes) ? frag_bytes
                                                       : (ws_size - hT_bytes);
    char* ws = (char*)d_ws;
    float* hT = (float*)(ws + hT_off);

    PA pa;
    pa.x = (const float*)d_in[0];
    pa.WihF = (const float*)d_in[1];  pa.WhhF = (const float*)d_in[2];
    pa.bihF = (const float*)d_in[3];  pa.bhhF = (const float*)d_in[4];
    pa.WihB = (const float*)d_in[5];  pa.WhhB = (const float*)d_in[6];
    pa.bihB = (const float*)d_in[7];  pa.bhhB = (const float*)d_in[8];
    pa.ws = ws;
    hipLaunchKernelGGL(phaseA_k, dim3(256), dim3(256), 0, stream, pa);

    PB pb;
    pb.WihF = (const float*)d_in[9];   pb.WhhF = (const float*)d_in[10];
    pb.bihF = (const float*)d_in[11];  pb.bhhF = (const float*)d_in[12];
    pb.WihB = (const float*)d_in[13];  pb.WhhB = (const float*)d_in[14];
    pb.bihB = (const float*)d_in[15];  pb.bhhB = (const float*)d_in[16];
    pb.ws = ws; pb.hT = hT;
    hipLaunchKernelGGL(phaseB_k, dim3(256), dim3(256), 0, stream, pb);

    PC pc;
    pc.hT = hT;
    pc.W1 = (const float*)d_in[17]; pc.b1 = (const float*)d_in[18];
    pc.W2 = (const float*)d_in[19]; pc.b2 = (const float*)d_in[20];
    pc.out = (float*)d_out;
    hipLaunchKernelGGL(head_k, dim3(BB/64), dim3(64), 0, stream, pc);
}